// Round 2
// baseline (253.439 us; speedup 1.0000x reference)
//
#include <hip/hip_runtime.h>

// CRF NLL: forward algorithm (linear-space, rescaled) + gold score.
// B=128 batches, S=512 steps, T=36 states (START=34, END=35).
// One wave per batch; lane j owns state j.  q_j = exp(alpha_j - C).
// Step: q' = (q . M) * exp(f_t),  M = exp(trans), M columns in 36 VGPRs/lane.
//
// R1 changes vs R0 (which was ~623 cyc/step, VALUBusy 4.6% -> ~90% stall):
//  - renorm via readlane(q,0) instead of 6-level shuffle max (alpha = C+log q
//    is invariant under any uniform rescale; state spread bounded ~2^18, and
//    2^18 * (2^14)^4 per 4 steps << 2^127, so lane-0 reference is range-safe)
//  - double-buffered 8-step load phases: next phase's 8 feats loads issued as
//    a batch at phase start -> ~1200 cyc slack vs ~900 cyc HBM latency
//  - no scalar tail: addresses clamp to step 511, q-update predicated on
//    t < tmax, renorm unconditional (invariant-preserving under masking)

namespace {
constexpr int kB = 128;
constexpr int kS = 512;
constexpr int kT = 36;
constexpr int kStart = 34;
constexpr int kEnd = 35;

__device__ __forceinline__ float readlane_f(float v, int lane) {
    return __builtin_bit_cast(float, __builtin_amdgcn_readlane(__builtin_bit_cast(int, v), lane));
}

__device__ __forceinline__ float wave_sum(float v) {
#pragma unroll
    for (int off = 32; off; off >>= 1) v += __shfl_xor(v, off, 64);
    return v;
}

__device__ __forceinline__ int wave_sum_i(int v) {
#pragma unroll
    for (int off = 32; off; off >>= 1) v += __shfl_xor(v, off, 64);
    return v;
}

__global__ __launch_bounds__(64, 1) void crf_nll_kernel(
    const float* __restrict__ feats,   // (B,S,T)
    const float* __restrict__ trans,   // (T,T)  [i,j] = prev i -> cur j
    const int* __restrict__ mask,      // (B,S)  contiguous prefix
    const int* __restrict__ tags,      // (B,S)
    float* __restrict__ out) {         // scalar
    const int b = blockIdx.x;
    const int j = threadIdx.x;  // lane = state index (j < 36 active)
    const float* fb = feats + (size_t)b * kS * kT;
    const int* mb = mask + b * kS;
    const int* tb = tags + b * kS;

    // ---- sequence length (contiguous-prefix mask) ----
    int len = 0;
    for (int k = j; k < kS; k += 64) len += mb[k];
    len = wave_sum_i(len);  // len in [256, 512]
    const int tmax = len;

    // ---- per-lane column of M = exp(trans) ----
    float Mcol[kT];
    float ME = 0.f;
    if (j < kT) {
#pragma unroll
        for (int i = 0; i < kT; ++i) Mcol[i] = __expf(trans[i * kT + j]);
        ME = __expf(trans[j * kT + kEnd]);
    } else {
#pragma unroll
        for (int i = 0; i < kT; ++i) Mcol[i] = 0.f;
    }

    // ---- init: alpha0 = feats[b,0,:] + trans[START,:] ----
    float a0 = -80.f;  // effectively 0 in linear space; lanes >= kT inert
    if (j < kT) a0 = fb[j] + trans[kStart * kT + j];
    float C = readlane_f(a0, 0);
    float q = __expf(a0 - C);  // q_0 = 1; all q in (0, ~2^18]

    // one step of the scan: q' = (q . M) * exp(f); predicated on t < tmax
    auto dostep = [&](float f, int t) {
        float v0 = 0.f, v1 = 0.f, v2 = 0.f, v3 = 0.f;
#pragma unroll
        for (int i = 0; i < kT; i += 4) {
            v0 = fmaf(readlane_f(q, i + 0), Mcol[i + 0], v0);
            v1 = fmaf(readlane_f(q, i + 1), Mcol[i + 1], v1);
            v2 = fmaf(readlane_f(q, i + 2), Mcol[i + 2], v2);
            v3 = fmaf(readlane_f(q, i + 3), Mcol[i + 3], v3);
        }
        const float nq = ((v0 + v1) + (v2 + v3)) * __expf(f);
        q = (t < tmax) ? nq : q;
    };
    // cheap renorm: scale by lane-0 q (alpha = C + log q invariant)
    auto renorm = [&]() {
        const float m = readlane_f(q, 0);
        q *= __builtin_amdgcn_rcpf(m);
        C += __logf(m);
    };

    // ---- main scan, double-buffered 8-step phases ----
    float bufA[8], bufB[8];
#pragma unroll
    for (int u = 0; u < 8; ++u)  // prologue: steps 1..8 (always in-bounds)
        bufA[u] = (j < kT) ? fb[(1 + u) * kT + j] : 0.f;

    int t0 = 1;
    while (t0 < tmax) {
        // phase A: issue loads for steps t0+8..t0+15, compute t0..t0+7
#pragma unroll
        for (int u = 0; u < 8; ++u) {
            const int tt = min(t0 + 8 + u, kS - 1);  // clamp: value masked later
            bufB[u] = (j < kT) ? fb[tt * kT + j] : 0.f;
        }
#pragma unroll
        for (int u = 0; u < 8; ++u) {
            dostep(bufA[u], t0 + u);
            if ((u & 3) == 3) renorm();
        }
        // phase B: issue loads for steps t0+16..t0+23, compute t0+8..t0+15
#pragma unroll
        for (int u = 0; u < 8; ++u) {
            const int tt = min(t0 + 16 + u, kS - 1);
            bufA[u] = (j < kT) ? fb[tt * kT + j] : 0.f;
        }
#pragma unroll
        for (int u = 0; u < 8; ++u) {
            dostep(bufB[u], t0 + 8 + u);
            if ((u & 3) == 3) renorm();
        }
        t0 += 16;
    }

    // ---- forward score: C + log(sum_i q_i * exp(trans[i][END])) ----
    const float ssum = wave_sum(q * ME);
    const float forward_b = C + __logf(ssum);

    // ---- gold score (parallel over time steps) ----
    float g = 0.f;
    for (int k = j; k < kS; k += 64) {
        if (k < len) {
            const int tg = tb[k];
            const int pv = (k == 0) ? kStart : tb[k - 1];
            g += fb[(size_t)k * kT + tg] + trans[pv * kT + tg];
        }
    }
    g = wave_sum(g);

    if (j == 0) {
        g += trans[tb[len - 1] * kT + kEnd];
        atomicAdd(out, (forward_b - g) * (1.0f / kB));
    }
}

}  // namespace

extern "C" void kernel_launch(void* const* d_in, const int* in_sizes, int n_in,
                              void* d_out, int out_size, void* d_ws, size_t ws_size,
                              hipStream_t stream) {
    const float* feats = (const float*)d_in[0];
    const float* trans = (const float*)d_in[1];
    const int* mask = (const int*)d_in[2];
    const int* tags = (const int*)d_in[3];
    float* out = (float*)d_out;

    hipMemsetAsync(out, 0, sizeof(float), stream);
    crf_nll_kernel<<<dim3(kB), dim3(64), 0, stream>>>(feats, trans, mask, tags, out);
}

// Round 3
// 146.998 us; speedup vs baseline: 1.7241x; 1.7241x over previous
//
#include <hip/hip_runtime.h>

// CRF NLL: forward algorithm (linear-space, rescaled) + gold score.
// B=128 batches, S=512 steps, T=36 states (START=34, END=35).
// One wave per batch; lane j owns state j.  q_j = exp(alpha_j - C).
// Step: q' = (q . M) * exp(f_t),  M = exp(trans).
//
// R2: R0/R1 profiled at VGPR_Count=36 -> Mcol[36]/buf arrays lived in
// SCRATCH, each step did ~36 scratch reloads (623-1000 cyc/step, VALUBusy
// 2-5%). This version stores M's column and the prefetch buffers as NAMED
// SCALARS via X-macros: no arrays -> no dynamic indexing -> no scratch.
// readlane lane indices are literals. Renorm via lane-0 reference (alpha =
// C + log q is invariant under uniform rescale; spread bounded ~2^18,
// growth < 2^60 per 4 steps << 2^127, so fp32-safe).

namespace {
constexpr int kB = 128;
constexpr int kS = 512;
constexpr int kT = 36;
constexpr int kStart = 34;
constexpr int kEnd = 35;

__device__ __forceinline__ float readlane_f(float v, int lane) {
    return __builtin_bit_cast(float, __builtin_amdgcn_readlane(__builtin_bit_cast(int, v), lane));
}

__device__ __forceinline__ float wave_sum(float v) {
#pragma unroll
    for (int off = 32; off; off >>= 1) v += __shfl_xor(v, off, 64);
    return v;
}

__device__ __forceinline__ int wave_sum_i(int v) {
#pragma unroll
    for (int off = 32; off; off >>= 1) v += __shfl_xor(v, off, 64);
    return v;
}

// n = term index, a = accumulator index (rotates 0..3 to break fma chains)
#define FOR36(X) \
    X(0, 0) X(1, 1) X(2, 2) X(3, 3) X(4, 0) X(5, 1) X(6, 2) X(7, 3) \
    X(8, 0) X(9, 1) X(10, 2) X(11, 3) X(12, 0) X(13, 1) X(14, 2) X(15, 3) \
    X(16, 0) X(17, 1) X(18, 2) X(19, 3) X(20, 0) X(21, 1) X(22, 2) X(23, 3) \
    X(24, 0) X(25, 1) X(26, 2) X(27, 3) X(28, 0) X(29, 1) X(30, 2) X(31, 3) \
    X(32, 0) X(33, 1) X(34, 2) X(35, 3)

#define MDECL(n, a) float m##n;
#define MINIT(n, a) m##n = __expf(trans[(n)*kT + jc]);
#define MDOT(n, a) v##a = fmaf(readlane_f(q, n), m##n, v##a);

__global__ __launch_bounds__(64, 1) void crf_nll_kernel(
    const float* __restrict__ feats,   // (B,S,T)
    const float* __restrict__ trans,   // (T,T)  [i,j] = prev i -> cur j
    const int* __restrict__ mask,      // (B,S)  contiguous prefix
    const int* __restrict__ tags,      // (B,S)
    float* __restrict__ out) {         // scalar
    const int b = blockIdx.x;
    const int j = threadIdx.x;                  // lane = state index
    const int jc = (j < kT) ? j : (kT - 1);     // lanes >= 36 mirror state 35
    const float* fbase = feats + (size_t)b * kS * kT;
    const float* fl = fbase + jc;               // per-lane feats column
    const int* mb = mask + b * kS;
    const int* tb = tags + b * kS;

    // ---- sequence length (contiguous-prefix mask) ----
    int len = 0;
    for (int k = j; k < kS; k += 64) len += mb[k];
    len = wave_sum_i(len);  // len in [256, 512]
    const int tmax = len;

    // ---- M = exp(trans) column jc, in 36 named registers ----
    FOR36(MDECL)
    FOR36(MINIT)
    const float ME = (j < kT) ? __expf(trans[j * kT + kEnd]) : 0.f;

    // ---- init: alpha0 = feats[b,0,:] + trans[START,:] ----
    const float a0 = fl[0] + trans[kStart * kT + jc];
    float C = readlane_f(a0, 0);
    float q = __expf(a0 - C);

    auto dostep = [&](float f, int t) {
        float v0 = 0.f, v1 = 0.f, v2 = 0.f, v3 = 0.f;
        FOR36(MDOT)
        const float nq = ((v0 + v1) + (v2 + v3)) * __expf(f);
        q = (t < tmax) ? nq : q;  // uniform predicate (masked steps keep q)
    };
    auto renorm = [&]() {  // uniform rescale; alpha = C + log q invariant
        const float mm = readlane_f(q, 0);
        q *= __builtin_amdgcn_rcpf(mm);
        C += __logf(mm);
    };

    // clamped feats load (value unused past tmax; address stays in-bounds)
#define LDT(t) fl[(size_t)(((t) < kS - 1) ? (t) : (kS - 1)) * kT]

    // ---- main scan: two 8-step phases per iteration, named buffers ----
    float pA0, pA1, pA2, pA3, pA4, pA5, pA6, pA7;
    float pB0, pB1, pB2, pB3, pB4, pB5, pB6, pB7;
    pA0 = LDT(1); pA1 = LDT(2); pA2 = LDT(3); pA3 = LDT(4);
    pA4 = LDT(5); pA5 = LDT(6); pA6 = LDT(7); pA7 = LDT(8);

    int t0 = 1;
    while (t0 < tmax) {
        // issue next phase's loads, then compute current phase
        pB0 = LDT(t0 + 8);  pB1 = LDT(t0 + 9);  pB2 = LDT(t0 + 10); pB3 = LDT(t0 + 11);
        pB4 = LDT(t0 + 12); pB5 = LDT(t0 + 13); pB6 = LDT(t0 + 14); pB7 = LDT(t0 + 15);
        dostep(pA0, t0 + 0); dostep(pA1, t0 + 1); dostep(pA2, t0 + 2); dostep(pA3, t0 + 3);
        renorm();
        dostep(pA4, t0 + 4); dostep(pA5, t0 + 5); dostep(pA6, t0 + 6); dostep(pA7, t0 + 7);
        renorm();

        pA0 = LDT(t0 + 16); pA1 = LDT(t0 + 17); pA2 = LDT(t0 + 18); pA3 = LDT(t0 + 19);
        pA4 = LDT(t0 + 20); pA5 = LDT(t0 + 21); pA6 = LDT(t0 + 22); pA7 = LDT(t0 + 23);
        dostep(pB0, t0 + 8);  dostep(pB1, t0 + 9);  dostep(pB2, t0 + 10); dostep(pB3, t0 + 11);
        renorm();
        dostep(pB4, t0 + 12); dostep(pB5, t0 + 13); dostep(pB6, t0 + 14); dostep(pB7, t0 + 15);
        renorm();
        t0 += 16;
    }

    // ---- forward score: C + log(sum_i q_i * exp(trans[i][END])) ----
    const float ssum = wave_sum(q * ME);  // lanes >= 36 contribute 0 (ME=0)
    const float forward_b = C + __logf(ssum);

    // ---- gold score (parallel over time steps) ----
    float g = 0.f;
    for (int k = j; k < kS; k += 64) {
        if (k < len) {
            const int tg = tb[k];
            const int pv = (k == 0) ? kStart : tb[k - 1];
            g += fbase[(size_t)k * kT + tg] + trans[pv * kT + tg];
        }
    }
    g = wave_sum(g);

    if (j == 0) {
        g += trans[tb[len - 1] * kT + kEnd];
        atomicAdd(out, (forward_b - g) * (1.0f / kB));
    }
}

}  // namespace

extern "C" void kernel_launch(void* const* d_in, const int* in_sizes, int n_in,
                              void* d_out, int out_size, void* d_ws, size_t ws_size,
                              hipStream_t stream) {
    const float* feats = (const float*)d_in[0];
    const float* trans = (const float*)d_in[1];
    const int* mask = (const int*)d_in[2];
    const int* tags = (const int*)d_in[3];
    float* out = (float*)d_out;

    hipMemsetAsync(out, 0, sizeof(float), stream);
    crf_nll_kernel<<<dim3(kB), dim3(64), 0, stream>>>(feats, trans, mask, tags, out);
}

// Round 4
// 142.274 us; speedup vs baseline: 1.7813x; 1.0332x over previous
//
#include <hip/hip_runtime.h>

// CRF NLL: forward algorithm (linear-space, rescaled) + gold score.
// B=128 batches, S=512 steps, T=36 states (START=34, END=35).
// One wave per batch; lane j owns state j.  q_j = exp(alpha_j - C).
// Step: q' = (q . M) * exp(f_t),  M = exp(trans).
//
// R3: R2 profiled at VGPR_Count=40 with a live set of ~62 -> the allocator
// was still spilling ~25-30 values per step to meet its DEFAULT occupancy
// target (~8 waves/EU -> ~64 VGPR budget); __launch_bounds__(64,1) did not
// lower it. Timing matched: 424 cyc/step = ~187 VALU issue + ~240 spill
// stall. Fix: amdgpu_waves_per_eu(1,1) -> 512-VGPR budget, no spills.
// Occupancy is irrelevant by construction (128 waves on 256 CUs).

namespace {
constexpr int kB = 128;
constexpr int kS = 512;
constexpr int kT = 36;
constexpr int kStart = 34;
constexpr int kEnd = 35;

__device__ __forceinline__ float readlane_f(float v, int lane) {
    return __builtin_bit_cast(float, __builtin_amdgcn_readlane(__builtin_bit_cast(int, v), lane));
}

__device__ __forceinline__ float wave_sum(float v) {
#pragma unroll
    for (int off = 32; off; off >>= 1) v += __shfl_xor(v, off, 64);
    return v;
}

__device__ __forceinline__ int wave_sum_i(int v) {
#pragma unroll
    for (int off = 32; off; off >>= 1) v += __shfl_xor(v, off, 64);
    return v;
}

// n = term index, a = accumulator index (rotates 0..3 to break fma chains)
#define FOR36(X) \
    X(0, 0) X(1, 1) X(2, 2) X(3, 3) X(4, 0) X(5, 1) X(6, 2) X(7, 3) \
    X(8, 0) X(9, 1) X(10, 2) X(11, 3) X(12, 0) X(13, 1) X(14, 2) X(15, 3) \
    X(16, 0) X(17, 1) X(18, 2) X(19, 3) X(20, 0) X(21, 1) X(22, 2) X(23, 3) \
    X(24, 0) X(25, 1) X(26, 2) X(27, 3) X(28, 0) X(29, 1) X(30, 2) X(31, 3) \
    X(32, 0) X(33, 1) X(34, 2) X(35, 3)

#define MDECL(n, a) float m##n;
#define MINIT(n, a) m##n = __expf(trans[(n)*kT + jc]);
#define MDOT(n, a) v##a = fmaf(readlane_f(q, n), m##n, v##a);

__global__ __attribute__((amdgpu_flat_work_group_size(64, 64),
                          amdgpu_waves_per_eu(1, 1)))
void crf_nll_kernel(
    const float* __restrict__ feats,   // (B,S,T)
    const float* __restrict__ trans,   // (T,T)  [i,j] = prev i -> cur j
    const int* __restrict__ mask,      // (B,S)  contiguous prefix
    const int* __restrict__ tags,      // (B,S)
    float* __restrict__ out) {         // scalar
    const int b = blockIdx.x;
    const int j = threadIdx.x;                  // lane = state index
    const int jc = (j < kT) ? j : (kT - 1);     // lanes >= 36 mirror state 35
    const float* fbase = feats + (size_t)b * kS * kT;
    const float* fl = fbase + jc;               // per-lane feats column
    const int* mb = mask + b * kS;
    const int* tb = tags + b * kS;

    // ---- sequence length (contiguous-prefix mask) ----
    int len = 0;
    for (int k = j; k < kS; k += 64) len += mb[k];
    len = wave_sum_i(len);  // len in [256, 512]
    const int tmax = len;

    // ---- M = exp(trans) column jc, in 36 named registers ----
    FOR36(MDECL)
    FOR36(MINIT)
    const float ME = (j < kT) ? __expf(trans[j * kT + kEnd]) : 0.f;

    // ---- init: alpha0 = feats[b,0,:] + trans[START,:] ----
    const float a0 = fl[0] + trans[kStart * kT + jc];
    float C = readlane_f(a0, 0);
    float q = __expf(a0 - C);

    auto dostep = [&](float f, int t) {
        float v0 = 0.f, v1 = 0.f, v2 = 0.f, v3 = 0.f;
        FOR36(MDOT)
        const float nq = ((v0 + v1) + (v2 + v3)) * __expf(f);
        q = (t < tmax) ? nq : q;  // uniform predicate (masked steps keep q)
    };
    auto renorm = [&]() {  // uniform rescale; alpha = C + log q invariant
        const float mm = readlane_f(q, 0);
        q *= __builtin_amdgcn_rcpf(mm);
        C += __logf(mm);
    };

    // clamped feats load (value unused past tmax; address stays in-bounds)
#define LDT(t) fl[(size_t)(((t) < kS - 1) ? (t) : (kS - 1)) * kT]

    // ---- main scan: two 8-step phases per iteration, named buffers ----
    float pA0, pA1, pA2, pA3, pA4, pA5, pA6, pA7;
    float pB0, pB1, pB2, pB3, pB4, pB5, pB6, pB7;
    pA0 = LDT(1); pA1 = LDT(2); pA2 = LDT(3); pA3 = LDT(4);
    pA4 = LDT(5); pA5 = LDT(6); pA6 = LDT(7); pA7 = LDT(8);

    int t0 = 1;
    while (t0 < tmax) {
        // issue next phase's loads, then compute current phase
        pB0 = LDT(t0 + 8);  pB1 = LDT(t0 + 9);  pB2 = LDT(t0 + 10); pB3 = LDT(t0 + 11);
        pB4 = LDT(t0 + 12); pB5 = LDT(t0 + 13); pB6 = LDT(t0 + 14); pB7 = LDT(t0 + 15);
        dostep(pA0, t0 + 0); dostep(pA1, t0 + 1); dostep(pA2, t0 + 2); dostep(pA3, t0 + 3);
        renorm();
        dostep(pA4, t0 + 4); dostep(pA5, t0 + 5); dostep(pA6, t0 + 6); dostep(pA7, t0 + 7);
        renorm();

        pA0 = LDT(t0 + 16); pA1 = LDT(t0 + 17); pA2 = LDT(t0 + 18); pA3 = LDT(t0 + 19);
        pA4 = LDT(t0 + 20); pA5 = LDT(t0 + 21); pA6 = LDT(t0 + 22); pA7 = LDT(t0 + 23);
        dostep(pB0, t0 + 8);  dostep(pB1, t0 + 9);  dostep(pB2, t0 + 10); dostep(pB3, t0 + 11);
        renorm();
        dostep(pB4, t0 + 12); dostep(pB5, t0 + 13); dostep(pB6, t0 + 14); dostep(pB7, t0 + 15);
        renorm();
        t0 += 16;
    }

    // ---- forward score: C + log(sum_i q_i * exp(trans[i][END])) ----
    const float ssum = wave_sum(q * ME);  // lanes >= 36 contribute 0 (ME=0)
    const float forward_b = C + __logf(ssum);

    // ---- gold score (parallel over time steps) ----
    float g = 0.f;
    for (int k = j; k < kS; k += 64) {
        if (k < len) {
            const int tg = tb[k];
            const int pv = (k == 0) ? kStart : tb[k - 1];
            g += fbase[(size_t)k * kT + tg] + trans[pv * kT + tg];
        }
    }
    g = wave_sum(g);

    if (j == 0) {
        g += trans[tb[len - 1] * kT + kEnd];
        atomicAdd(out, (forward_b - g) * (1.0f / kB));
    }
}

}  // namespace

extern "C" void kernel_launch(void* const* d_in, const int* in_sizes, int n_in,
                              void* d_out, int out_size, void* d_ws, size_t ws_size,
                              hipStream_t stream) {
    const float* feats = (const float*)d_in[0];
    const float* trans = (const float*)d_in[1];
    const int* mask = (const int*)d_in[2];
    const int* tags = (const int*)d_in[3];
    float* out = (float*)d_out;

    hipMemsetAsync(out, 0, sizeof(float), stream);
    crf_nll_kernel<<<dim3(kB), dim3(64), 0, stream>>>(feats, trans, mask, tags, out);
}